// Round 3
// baseline (354.374 us; speedup 1.0000x reference)
//
#include <hip/hip_runtime.h>
#include <math.h>

#define NMS_THR 0.3f

__device__ __forceinline__ float fmul(float a, float b){ return __fmul_rn(a,b); }
__device__ __forceinline__ float fadd(float a, float b){ return __fadd_rn(a,b); }
__device__ __forceinline__ float fsub(float a, float b){ return __fsub_rn(a,b); }

__device__ __forceinline__ unsigned long long rdlane64(unsigned int lo, unsigned int hi, int a) {
    unsigned long long l = (unsigned int)__builtin_amdgcn_readlane((int)lo, a);
    unsigned long long h = (unsigned int)__builtin_amdgcn_readlane((int)hi, a);
    return (h << 32) | l;
}

// K1: per-row softmax max/sum + argmax + per-class regression decode. One wave per row.
__global__ __launch_bounds__(256) void k_decode(
    const float* __restrict__ prop, const float* __restrict__ reg,
    const float* __restrict__ clss, const float* __restrict__ stds,
    const int* __restrict__ imgsz,
    float* __restrict__ boxes, float* __restrict__ key,
    float* __restrict__ score, int* __restrict__ cls,
    int N, int C)
{
    int wid  = threadIdx.x >> 6;
    int lane = threadIdx.x & 63;
    int n = blockIdx.x * 4 + wid;
    if (n >= N) return;
    const float* row = clss + (long)n * C;
    float ninf = -__builtin_inff();
    float x0 = (lane < C)      ? row[lane]      : ninf;
    float x1 = (lane + 64 < C) ? row[lane + 64] : ninf;
    float m = fmaxf(x0, x1);
    for (int o = 32; o > 0; o >>= 1) m = fmaxf(m, __shfl_xor(m, o));
    float e0 = (lane < C)      ? expf(x0 - m) : 0.0f;
    float e1 = (lane + 64 < C) ? expf(x1 - m) : 0.0f;
    float s = e0 + e1;
    for (int o = 32; o > 0; o >>= 1) s += __shfl_xor(s, o);
    float bv; int bi;
    if (e0 >= e1) { bv = e0; bi = lane; } else { bv = e1; bi = lane + 64; }
    for (int o = 32; o > 0; o >>= 1) {
        float ov = __shfl_xor(bv, o);
        int   oi = __shfl_xor(bi, o);
        if (ov > bv || (ov == bv && oi < bi)) { bv = ov; bi = oi; }
    }
    if (lane == 0) {
        float sc = 1.0f / s;
        int   c  = bi;
        int   valid = (c != 0);
        float p0 = prop[n*4+0], p1 = prop[n*4+1], p2 = prop[n*4+2], p3 = prop[n*4+3];
        float w  = fsub(p2, p0), h = fsub(p3, p1);
        float cx = fadd(p0, fmul(0.5f, w));
        float cy = fadd(p1, fmul(0.5f, h));
        const float* rr = reg + (long)n * C * 4 + (long)c * 4;
        float t0 = fmul(rr[0], stds[0]);
        float t1 = fmul(rr[1], stds[1]);
        float t2 = fmul(rr[2], stds[2]);
        float t3 = fmul(rr[3], stds[3]);
        float px = fadd(cx, fmul(w, t0));
        float py = fadd(cy, fmul(h, t1));
        float pw = fmul(w, expf(t2));
        float ph = fmul(h, expf(t3));
        float hi = (float)(imgsz[0] - 1);
        float bx1 = fminf(fmaxf(fsub(px, fmul(0.5f, pw)), 0.0f), hi);
        float by1 = fminf(fmaxf(fsub(py, fmul(0.5f, ph)), 0.0f), hi);
        float bx2 = fminf(fmaxf(fadd(px, fmul(0.5f, pw)), 0.0f), hi);
        float by2 = fminf(fmaxf(fadd(py, fmul(0.5f, ph)), 0.0f), hi);
        boxes[n*4+0]=bx1; boxes[n*4+1]=by1; boxes[n*4+2]=bx2; boxes[n*4+3]=by2;
        score[n] = sc;
        cls[n]   = c;
        key[n]   = valid ? sc : ninf;
    }
}

// K2: stable descending rank sort. 64 rows/block, 4 j-strips of 256 threads.
// Block 0 additionally computes nValid (count of keys != -inf).
__global__ __launch_bounds__(256) void k_rank(
    const float* __restrict__ key, const float* __restrict__ boxes,
    float* __restrict__ boxesSorted, float* __restrict__ areaSorted,
    float* __restrict__ keySorted, int* __restrict__ rank,
    int* __restrict__ nValidPtr, int N)
{
    extern __shared__ float lkey[];     // N floats
    __shared__ int part[256];
    int tid = threadIdx.x;
    for (int j = tid; j < N; j += 256) lkey[j] = key[j];
    __syncthreads();

    int i = blockIdx.x * 64 + (tid & 63);
    int s = tid >> 6;
    int Q = (N + 3) >> 2;
    int r_part = 0;
    if (i < N) {
        float ki = lkey[i];
        int j0 = s * Q, j1 = min(N, j0 + Q);
        for (int j = j0; j < j1; ++j) {
            float kj = lkey[j];
            r_part += (kj > ki) || (kj == ki && j < i);   // stable
        }
    }
    part[tid] = r_part;
    __syncthreads();

    if (tid < 64 && i < N) {
        int r = part[tid] + part[tid+64] + part[tid+128] + part[tid+192];
        float ki = lkey[i];
        rank[i] = r;
        float b0 = boxes[i*4+0], b1 = boxes[i*4+1], b2 = boxes[i*4+2], b3 = boxes[i*4+3];
        boxesSorted[r*4+0]=b0; boxesSorted[r*4+1]=b1; boxesSorted[r*4+2]=b2; boxesSorted[r*4+3]=b3;
        areaSorted[r] = fmul(fsub(b2,b0), fsub(b3,b1));
        keySorted[r]  = ki;
    }

    if (blockIdx.x == 0) {
        __syncthreads();
        float ninf = -__builtin_inff();
        int inv = 0;
        for (int j = tid; j < N; j += 256) inv += (lkey[j] == ninf);
        part[tid] = inv;
        __syncthreads();
        if (tid == 0) {
            int t = 0;
            for (int q = 0; q < 256; ++q) t += part[q];
            nValidPtr[0] = N - t;
        }
    }
}

// K3: suppression bitmask, ROW-MAJOR: mask[i*W + w]; plus diag[i] (word i>>6)
// and sdiag[i] (word (i>>6)+1, or 0 if out of range).
__global__ __launch_bounds__(256) void k_mask(
    const float* __restrict__ bs, const float* __restrict__ areas,
    const float* __restrict__ keySorted, unsigned long long* __restrict__ mask,
    unsigned long long* __restrict__ diag, unsigned long long* __restrict__ sdiag,
    int N, int W)
{
    int wid  = threadIdx.x >> 6;
    int lane = threadIdx.x & 63;
    int i = blockIdx.x * 4 + wid;
    if (i >= N) return;
    if (keySorted[i] == -__builtin_inff()) return;   // invalid row: never read
    float ax1 = bs[i*4+0], ay1 = bs[i*4+1], ax2 = bs[i*4+2], ay2 = bs[i*4+3];
    float aa  = areas[i];
    int w0 = i >> 6;
    if (lane == 0 && w0 + 1 >= W) sdiag[i] = 0ULL;
    for (int w = w0; w < W; ++w) {
        int j = w*64 + lane;
        int bit = 0;
        if (j < N && j > i) {
            float bx1 = bs[j*4+0], by1 = bs[j*4+1], bx2 = bs[j*4+2], by2 = bs[j*4+3];
            float ba  = areas[j];
            float ix1 = fmaxf(ax1,bx1), iy1 = fmaxf(ay1,by1);
            float ix2 = fminf(ax2,bx2), iy2 = fminf(ay2,by2);
            float iw = fmaxf(fsub(ix2,ix1), 0.0f);
            float ih = fmaxf(fsub(iy2,iy1), 0.0f);
            float inter = fmul(iw, ih);
            float denom = fadd(fsub(fadd(aa, ba), inter), 1e-9f);
            float iou = inter / denom;
            bit = (iou > NMS_THR) ? 1 : 0;
        }
        unsigned long long bm = __ballot(bit);
        if (lane == 0) {
            mask[(long)i*W + w] = bm;
            if (w == w0)     diag[i]  = bm;
            if (w == w0 + 1) sdiag[i] = bm;
        }
    }
}

// K4: chunked greedy scan, single wave, software-pipelined.
// removed-bitmap distributed: lane L owns words L (r0) and 64+L (r1).
// Resolve is a pure scalar chain (ctz + readlane of diag). inc for chunk c+1
// comes from sdiag (no dependence on this chunk's row loads); row-mask loads
// park in a 16-row pending register file, ORed one chunk later (latency hidden
// under the next resolve).
__global__ __launch_bounds__(64) void k_scan(
    const unsigned long long* __restrict__ mask,
    const unsigned long long* __restrict__ diag,
    const unsigned long long* __restrict__ sdiag,
    const int* __restrict__ nValidPtr,
    int* __restrict__ keepSorted, int N, int W)
{
    int lane = threadIdx.x;
    for (int i = lane; i < N; i += 64) keepSorted[i] = 0;
    int nValid = nValidPtr[0];
    int nChunks = (nValid + 63) >> 6;
    unsigned long long r0 = 0ULL, r1 = 0ULL;
    int l2 = lane + 64;

    unsigned long long pend0[16], pend1[16];
#pragma unroll
    for (int q = 0; q < 16; ++q) { pend0[q] = 0ULL; pend1[q] = 0ULL; }

    unsigned long long D = 0ULL, S = 0ULL;
    if (lane < nValid) { D = diag[lane]; S = sdiag[lane]; }
    unsigned long long inc = 0ULL;

    for (int c = 0; c < nChunks; ++c) {
        int base = c << 6;
        // prefetch next chunk's diag/sdiag (coalesced, off critical path)
        unsigned long long Dn = 0ULL, Sn = 0ULL;
        int nrow = base + 64 + lane;
        if (c + 1 < nChunks && nrow < nValid) { Dn = diag[nrow]; Sn = sdiag[nrow]; }

        int nv = nValid - base;
        unsigned long long validBits = (nv >= 64) ? ~0ULL : ((1ULL << nv) - 1ULL);
        unsigned long long cand = validBits & ~inc;
        unsigned long long keepM = 0ULL, sacc = 0ULL;
        unsigned int Dlo = (unsigned int)D, Dhi = (unsigned int)(D >> 32);
        unsigned int Slo = (unsigned int)S, Shi = (unsigned int)(S >> 32);
        while (cand) {
            int a = __builtin_ctzll(cand);
            unsigned long long bit = 1ULL << a;
            keepM |= bit;
            unsigned long long Da = rdlane64(Dlo, Dhi, a);
            sacc |= rdlane64(Slo, Shi, a);
            cand &= ~bit;
            cand &= ~Da;
        }
        if (base + lane < N) keepSorted[base + lane] = (int)((keepM >> lane) & 1ULL);

        // OR previous chunk's pending row masks (waitcnt lands here, hidden by
        // the resolve above).
        {
            unsigned long long a0 = 0ULL, a1 = 0ULL;
#pragma unroll
            for (int q = 0; q < 16; ++q) { a0 |= pend0[q]; a1 |= pend1[q]; }
            r0 |= a0; r1 |= a1;
        }

        // issue this chunk's kept-row loads into pending (coalesced row-major)
        unsigned long long kb = keepM;
#pragma unroll
        for (int q = 0; q < 16; ++q) {
            if (kb) {
                int a = __builtin_ctzll(kb); kb &= kb - 1ULL;
                const unsigned long long* rp = mask + (size_t)(base + a) * W;
                pend0[q] = (lane < W) ? rp[lane] : 0ULL;
                pend1[q] = (l2 < W)   ? rp[l2]   : 0ULL;
            } else { pend0[q] = 0ULL; pend1[q] = 0ULL; }
        }
        // overflow (>16 kept in one chunk): OR immediately
        while (kb) {
            unsigned long long x0 = 0ULL, x1 = 0ULL, y0 = 0ULL, y1 = 0ULL;
            { int a = __builtin_ctzll(kb); kb &= kb - 1ULL;
              const unsigned long long* rp = mask + (size_t)(base + a) * W;
              x0 = (lane < W) ? rp[lane] : 0ULL; x1 = (l2 < W) ? rp[l2] : 0ULL; }
            if (kb) { int a = __builtin_ctzll(kb); kb &= kb - 1ULL;
              const unsigned long long* rp = mask + (size_t)(base + a) * W;
              y0 = (lane < W) ? rp[lane] : 0ULL; y1 = (l2 < W) ? rp[l2] : 0ULL; }
            r0 |= x0 | y0; r1 |= x1 | y1;
        }

        // inc for next chunk: word c+1 of removed-map. Chunks <= c-1 are in r
        // (pending ORed above); chunk c's contribution arrives via sdiag.
        int wn = c + 1;
        unsigned long long rw = (wn < 64) ? __shfl(r0, wn) : __shfl(r1, wn - 64);
        inc = rw | sacc;

        D = Dn; S = Sn;
    }
}

// K5: write outputs in original order: boxes*m, score*m, float(cls*keep).
__global__ __launch_bounds__(256) void k_out(
    const float* __restrict__ boxes, const float* __restrict__ score,
    const int* __restrict__ cls, const int* __restrict__ rank,
    const int* __restrict__ keepSorted,
    float* __restrict__ out, int N)
{
    int n = blockIdx.x * blockDim.x + threadIdx.x;
    if (n >= N) return;
    int k = keepSorted[rank[n]];
    float m = (float)k;
    out[n*4+0] = boxes[n*4+0]*m;
    out[n*4+1] = boxes[n*4+1]*m;
    out[n*4+2] = boxes[n*4+2]*m;
    out[n*4+3] = boxes[n*4+3]*m;
    out[(long)N*4 + n] = score[n]*m;
    out[(long)N*5 + n] = (float)(cls[n] * k);
}

extern "C" void kernel_launch(void* const* d_in, const int* in_sizes, int n_in,
                              void* d_out, int out_size, void* d_ws, size_t ws_size,
                              hipStream_t stream) {
    const float* prop = (const float*)d_in[0];
    const float* reg  = (const float*)d_in[1];
    const float* clss = (const float*)d_in[2];
    const float* stds = (const float*)d_in[3];
    const int*   img  = (const int*)d_in[4];

    int N = in_sizes[0] / 4;
    int C = in_sizes[2] / N;
    int W = (N + 63) / 64;

    char* ws = (char*)d_ws;
    size_t off = 0;
    float* boxes       = (float*)(ws + off); off += (size_t)N*4*sizeof(float);
    float* key         = (float*)(ws + off); off += (size_t)N*sizeof(float);
    float* score       = (float*)(ws + off); off += (size_t)N*sizeof(float);
    int*   cls         = (int*)  (ws + off); off += (size_t)N*sizeof(int);
    int*   rank        = (int*)  (ws + off); off += (size_t)N*sizeof(int);
    float* boxesSorted = (float*)(ws + off); off += (size_t)N*4*sizeof(float);
    float* areaSorted  = (float*)(ws + off); off += (size_t)N*sizeof(float);
    float* keySorted   = (float*)(ws + off); off += (size_t)N*sizeof(float);
    int*   keepSorted  = (int*)  (ws + off); off += (size_t)N*sizeof(int);
    int*   nValid      = (int*)  (ws + off); off += sizeof(int);
    off = (off + 7) & ~(size_t)7;
    unsigned long long* mask  = (unsigned long long*)(ws + off);
    off += (size_t)N * W * sizeof(unsigned long long);
    unsigned long long* diag  = (unsigned long long*)(ws + off);
    off += (size_t)N * sizeof(unsigned long long);
    unsigned long long* sdiag = (unsigned long long*)(ws + off);
    off += (size_t)N * sizeof(unsigned long long);
    (void)ws_size; (void)out_size; (void)n_in;

    int rowBlocks  = (N + 3) / 4;
    int thrBlocks  = (N + 255) / 256;
    int rankBlocks = (N + 63) / 64;

    k_decode<<<rowBlocks, 256, 0, stream>>>(prop, reg, clss, stds, img,
                                            boxes, key, score, cls, N, C);
    k_rank<<<rankBlocks, 256, (size_t)N*sizeof(float), stream>>>(key, boxes,
                                            boxesSorted, areaSorted, keySorted, rank, nValid, N);
    k_mask<<<rowBlocks, 256, 0, stream>>>(boxesSorted, areaSorted, keySorted,
                                          mask, diag, sdiag, N, W);
    k_scan<<<1, 64, 0, stream>>>(mask, diag, sdiag, nValid, keepSorted, N, W);
    k_out<<<thrBlocks, 256, 0, stream>>>(boxes, score, cls, rank, keepSorted,
                                         (float*)d_out, N);
}